// Round 6
// baseline (306.380 us; speedup 1.0000x reference)
//
#include <hip/hip_runtime.h>
#include <hip/hip_bf16.h>
#include <stdint.h>

typedef __bf16 bf16;
typedef unsigned char u8;
typedef bf16 bf16x4_t __attribute__((ext_vector_type(4)));
typedef bf16 bf16x8_t __attribute__((ext_vector_type(8)));
typedef float floatx4_t __attribute__((ext_vector_type(4)));

#define NB 8
#define SQ 2048
#define SKV 2048
#define DIN 512
#define DOUT 512

// scores = (q*4)(k*4)/16/sqrt(512): 1/(16*sqrt(512))
#define SCORE_SCALE 0.0027621358640099513f
// expS stored as e/16 to stay under fp8 e4m3 max (448)
#define P_STORE_SCALE 0.0625f
#define P_UNDO_SCALE 16.0f

__device__ __forceinline__ void load_lds16(const void* g, void* l) {
    __builtin_amdgcn_global_load_lds(
        (const __attribute__((address_space(1))) unsigned int*)g,
        (__attribute__((address_space(3))) unsigned int*)l, 16, 0, 0);
}

__device__ __forceinline__ u8 to_fp8(float f) {
    int v = __builtin_amdgcn_cvt_pk_fp8_f32(f, 0.f, 0, false);
    return (u8)(v & 0xff);
}
__device__ __forceinline__ unsigned int pack_fp8x4(float a, float b, float c, float d) {
    int lo = __builtin_amdgcn_cvt_pk_fp8_f32(a, b, 0, false);
    int all = __builtin_amdgcn_cvt_pk_fp8_f32(c, d, lo, true);
    return (unsigned int)all;
}

// 16-B-granule XOR swizzle within each 64-B k-block, key = (row>>1)&3.
// LDS row stride is 64 B = 16 banks, so bank group = {row&1, granule}. Keying
// the XOR off (row>>1)&3 (NOT row&3, whose bit0 duplicates the row&1 bank bit)
// spreads the 8 same-granule rows of a quad across all 8 bank groups -> 2-way
// (free). Producers write with it; LDS readers undo it. Applied to BOTH fp8
// and bf16 operand buffers (all are consumed only through the mainloops).
__device__ __forceinline__ int swz_off(int row, int col) {
    return (col & ~63) | ((((col >> 4) & 3) ^ ((row >> 1) & 3)) << 4) | (col & 15);
}

// bf16 cast helper: 8 consecutive f32 -> one 16-B swizzled store.
__device__ __forceinline__ void cast_bf16_16B(const float4* s4, u8* d, int t, int rs) {
    const long long b0 = (long long)t * 16;
    const int row = (int)(b0 >> rs);
    const int cb = (int)(b0 & ((1 << rs) - 1));
    float4 f0 = s4[t * 2], f1 = s4[t * 2 + 1];
    bf16x8_t o = { (bf16)f0.x, (bf16)f0.y, (bf16)f0.z, (bf16)f0.w,
                   (bf16)f1.x, (bf16)f1.y, (bf16)f1.z, (bf16)f1.w };
    *(bf16x8_t*)&d[((long long)row << rs) + swz_off(row, cb)] = o;
}

// ---------------- cast: query/key -> fp8(swz), value -> bf16(swz) ----------------
// Critical-path casts ONLY (consumed by proj_gemm). offset/Woff/lbuf casts are
// horizontally fused into g_gemm/proj_gemm where CUs idle. Every store is one
// full 16-B instruction at a swizzle-granule boundary.
struct CastArgs {
    const float* src[3];
    void* dst[3];
    int n[3];        // work items per slice (threads)
    int mode[3];     // 0=bf16 swz, 1=fp8 swz
    int rowshift[3]; // log2(dst row bytes)
};
__global__ __launch_bounds__(256) void cast_many(CastArgs a) {
    const int z = blockIdx.z;
    const int t = blockIdx.x * 256 + threadIdx.x;
    if (t >= a.n[z]) return;
    const float4* s4 = (const float4*)a.src[z];
    u8* d = (u8*)a.dst[z];
    const int rs = a.rowshift[z];
    if (a.mode[z] == 1) {
        const long long b0 = (long long)t * 16;
        const int row = (int)(b0 >> rs);
        const int cb = (int)(b0 & ((1 << rs) - 1));
        u8* dst = &d[((long long)row << rs) + swz_off(row, cb)];
        float4 f[4];
#pragma unroll
        for (int k = 0; k < 4; ++k) f[k] = s4[t * 4 + k];
        uint4 o;
        o.x = pack_fp8x4(f[0].x, f[0].y, f[0].z, f[0].w);
        o.y = pack_fp8x4(f[1].x, f[1].y, f[1].z, f[1].w);
        o.z = pack_fp8x4(f[2].x, f[2].y, f[2].z, f[2].w);
        o.w = pack_fp8x4(f[3].x, f[3].y, f[3].z, f[3].w);
        *(uint4*)dst = o;
    } else {
        cast_bf16_16B(s4, d, t, rs);
    }
}

// ---------------- weight transpose f32[512,512] -> fp8(swz, x4) for Wq/Wk, bf16(swz) for Wv ----------------
struct TWArgs { const float* src[3]; void* dst[3]; };
__global__ void transpose_w(TWArgs a) {
    __shared__ float t[32][33];
    const float* src = a.src[blockIdx.z];
    int tx = threadIdx.x, ty = threadIdx.y;
    int x0 = blockIdx.x * 32, y0 = blockIdx.y * 32;
#pragma unroll
    for (int j = 0; j < 4; ++j)
        t[ty + 8 * j][tx] = src[(y0 + ty + 8 * j) * DIN + x0 + tx];
    __syncthreads();
    if (blockIdx.z <= 1) {
        u8* d8 = (u8*)a.dst[blockIdx.z];
#pragma unroll
        for (int j = 0; j < 4; ++j) {
            int row = x0 + ty + 8 * j, col = y0 + tx;
            d8[row * 512 + swz_off(row, col)] = to_fp8(t[tx][ty + 8 * j] * 4.0f);
        }
    } else {
        u8* db = (u8*)a.dst[2];
#pragma unroll
        for (int j = 0; j < 4; ++j) {
            int row = x0 + ty + 8 * j, cb = (y0 + tx) * 2;
            *(bf16*)&db[(long long)row * 1024 + swz_off(row, cb)] = (bf16)t[tx][ty + 8 * j];
        }
    }
}

// ---------------- bf16 NT mainloop, BK=32, double-buffered + pipelined ----------------
__device__ __forceinline__ void gemm_mainloop(
    floatx4_t (&acc)[4][4], const bf16* __restrict__ Ap, const bf16* __restrict__ Bp,
    int lda, int ldb, int K, bf16* As, bf16* Bs, int wave, int lane)
{
    const int wm = (wave & 1) * 64, wn = (wave >> 1) * 64;
    const int lm = lane & 15, quad = lane >> 4;
    const int srow = lane >> 2, scol = (lane & 3) * 8;
    const int key = (lm >> 1) & 3;

    auto STAGE = [&](int buf, int k0) {
#pragma unroll
        for (int t = 0; t < 2; ++t) {
            const int r0 = (wave * 2 + t) * 16;
            load_lds16(Ap + (long long)(r0 + srow) * lda + (k0 + scol),
                       &As[buf * 4096 + r0 * 32]);
            load_lds16(Bp + (long long)(r0 + srow) * ldb + (k0 + scol),
                       &Bs[buf * 4096 + r0 * 32]);
        }
    };

    STAGE(0, 0);
    __syncthreads();
    int cur = 0;
    for (int k0 = 0; k0 < K; k0 += 32) {
        if (k0 + 32 < K) STAGE(cur ^ 1, k0 + 32);
        bf16x8_t af[4], bfr[4];
#pragma unroll
        for (int i = 0; i < 4; ++i)
            af[i] = *(const bf16x8_t*)&As[cur * 4096 + (wm + i * 16 + lm) * 32 + (quad ^ key) * 8];
#pragma unroll
        for (int i = 0; i < 4; ++i)
            bfr[i] = *(const bf16x8_t*)&Bs[cur * 4096 + (wn + i * 16 + lm) * 32 + (quad ^ key) * 8];
#pragma unroll
        for (int i = 0; i < 4; ++i)
#pragma unroll
            for (int j = 0; j < 4; ++j)
                acc[i][j] = __builtin_amdgcn_mfma_f32_16x16x32_bf16(af[i], bfr[j], acc[i][j], 0, 0, 0);
        __syncthreads();
        cur ^= 1;
    }
}

// ---------------- fp8 NT mainloop, BK=64, double-buffered + pipelined ----------------
__device__ __forceinline__ void gemm_mainloop_fp8(
    floatx4_t (&acc)[4][4], const u8* __restrict__ Ap, const u8* __restrict__ Bp,
    int lda, int ldb, int K, u8* As, u8* Bs, int wave, int lane)
{
    const int wm = (wave & 1) * 64, wn = (wave >> 1) * 64;
    const int lm = lane & 15, quad = lane >> 4;
    const int srow = lane >> 2, scol = (lane & 3) * 16;  // 16 rows x 64 B per inst
    const int key = (lm >> 1) & 3;
    const int inner = (quad & 1) * 8;
    const int gh = quad >> 1;

    auto STAGE = [&](int buf, int k0) {
#pragma unroll
        for (int t = 0; t < 2; ++t) {
            const int r0 = (wave * 2 + t) * 16;
            load_lds16(Ap + (long long)(r0 + srow) * lda + k0 + scol, &As[buf * 8192 + r0 * 64]);
            load_lds16(Bp + (long long)(r0 + srow) * ldb + k0 + scol, &Bs[buf * 8192 + r0 * 64]);
        }
    };

    STAGE(0, 0);
    __syncthreads();
    int cur = 0;
    for (int k0 = 0; k0 < K; k0 += 64) {
        if (k0 + 64 < K) STAGE(cur ^ 1, k0 + 64);
#pragma unroll
        for (int p = 0; p < 2; ++p) {
            const int gL = p * 2 + gh;
            const int koff = ((gL ^ key) << 4) + inner;  // undo producer swizzle
            long long a[4], b[4];
#pragma unroll
            for (int i = 0; i < 4; ++i)
                a[i] = *(const long long*)&As[cur * 8192 + (wm + i * 16 + lm) * 64 + koff];
#pragma unroll
            for (int i = 0; i < 4; ++i)
                b[i] = *(const long long*)&Bs[cur * 8192 + (wn + i * 16 + lm) * 64 + koff];
#pragma unroll
            for (int i = 0; i < 4; ++i)
#pragma unroll
                for (int j = 0; j < 4; ++j)
                    acc[i][j] = __builtin_amdgcn_mfma_f32_16x16x32_fp8_fp8(a[i], b[j], acc[i][j], 0, 0, 0);
        }
        __syncthreads();
        cur ^= 1;
    }
}

// ---------------- phase 1: Q/K projections (fp8) + VT projection (bf16) + Woff cast ----------------
// ids [0,1024): fp8 Q/K proj. ids [1024,1536): VT proj. ids [1536,2048): Woff->bf16 cast
// (fused here so Woffb is ready for g_gemm; these blocks run in idle capacity).
__global__ __launch_bounds__(256) void proj_gemm(
    const u8* __restrict__ query8, const u8* __restrict__ key8,
    const u8* __restrict__ WqT8, const u8* __restrict__ WkT8,
    u8* __restrict__ Qb8, u8* __restrict__ Kb8,
    const bf16* __restrict__ valueb, const bf16* __restrict__ WvT,
    bf16* __restrict__ VT, u8* __restrict__ VT8,
    const float* __restrict__ Woff, bf16* __restrict__ Woffb)
{
    __shared__ __align__(16) u8 smem[32768];
    const int tid = threadIdx.x;
    const int id = blockIdx.x;
    if (id >= 1536) {
        // Woff cast: 131072 threads, 8 f32 -> 16-B bf16 swz store, rows = 4096 B
        const int t = (id - 1536) * 256 + tid;
        cast_bf16_16B((const float4*)Woff, (u8*)Woffb, t, 12);
        return;
    }
    const int wave = tid >> 6, lane = tid & 63;
    const int wm = (wave & 1) * 64, wn = (wave >> 1) * 64;
    const int lm = lane & 15, quad = lane >> 4;

    floatx4_t acc[4][4];
#pragma unroll
    for (int i = 0; i < 4; ++i)
#pragma unroll
        for (int j = 0; j < 4; ++j) acc[i][j] = 0.0f;

    if (id < 1024) {
        const int xcd = id & 7, t = id >> 3, m = t & 3;
        const int gg = xcd + 8 * (t >> 2);
        const int y = gg & 127, z = gg >> 7;
        const u8* Ap = (z ? key8 : query8) + (long long)y * 128 * DIN;
        const u8* Bp = (z ? WkT8 : WqT8) + (long long)m * 128 * DIN;
        gemm_mainloop_fp8(acc, Ap, Bp, DIN, DIN, DIN, smem, smem + 16384, wave, lane);
        u8* C = z ? Kb8 : Qb8;
#pragma unroll
        for (int i = 0; i < 4; ++i)
#pragma unroll
            for (int j = 0; j < 4; ++j) {
                const int row0 = y * 128 + wm + i * 16 + quad * 4;
                const int col = m * 128 + wn + j * 16 + lm;
#pragma unroll
                for (int r = 0; r < 4; ++r)
                    C[(long long)(row0 + r) * DOUT + swz_off(row0 + r, col)] = to_fp8(acc[i][j][r]);
            }
    } else {
        const int id2 = id - 1024;
        const int z = id2 & 7, r2 = id2 >> 3;
        const int ym = r2 & 3, xn = r2 >> 2;
        const bf16* Ap = WvT + (long long)ym * 128 * DIN;
        const bf16* Bp = valueb + (long long)z * (SKV * DIN) + (long long)xn * 128 * DIN;
        gemm_mainloop(acc, Ap, Bp, DIN, DIN, DIN, (bf16*)smem, (bf16*)(smem + 16384), wave, lane);
        u8* C = (u8*)(VT + (long long)z * (DOUT * SKV));
        u8* C8 = VT8 + (long long)z * (DOUT * SKV);
#pragma unroll
        for (int i = 0; i < 4; ++i)
#pragma unroll
            for (int j = 0; j < 4; ++j) {
                const int row0 = ym * 128 + wm + i * 16 + quad * 4;
                const int col = xn * 128 + wn + j * 16 + lm;
#pragma unroll
                for (int r = 0; r < 4; ++r) {
                    float v = acc[i][j][r];
                    const int rr = row0 + r;
                    *(bf16*)&C[(long long)rr * (SKV * 2) + swz_off(rr, col * 2)] = (bf16)v;
                    C8[(long long)rr * SKV + swz_off(rr, col)] = to_fp8(v);
                }
            }
    }
}

// ---------------- G split-K2 + fused offset cast + lbuf zero ----------------
// ids [0,256): gemm (z=id%8, h=(id>>3)&1, x=(id>>4)&3, y=(id>>6)&3) — only
// 1 block/CU, so ids [256,4352) do the offset->bf16 cast and ids [4352,4356)
// zero lbuf, filling the idle CUs. offsetb/lbuf are consumed by later launches.
__global__ __launch_bounds__(256) void g_gemm(
    const bf16* __restrict__ VT, const bf16* __restrict__ Woffb,
    float* __restrict__ G32a, float* __restrict__ G32b,
    const float* __restrict__ offset, bf16* __restrict__ offsetb,
    float* __restrict__ lbuf)
{
    __shared__ __align__(16) u8 smem[32768];
    const int tid = threadIdx.x;
    const int id = blockIdx.x;
    if (id >= 4352) {
        // zero lbuf: 16384 floats, 4 blocks x 256 thr x 4 float4
        float4* d4 = (float4*)lbuf;
        const int t = (id - 4352) * 256 + tid;
#pragma unroll
        for (int k = 0; k < 4; ++k)
            d4[t * 4 + k] = make_float4(0.f, 0.f, 0.f, 0.f);
        return;
    }
    if (id >= 256) {
        // offset cast: 1048576 threads, 8 f32 -> 16-B bf16 swz store, rows = 1024 B
        const int t = (id - 256) * 256 + tid;
        cast_bf16_16B((const float4*)offset, (u8*)offsetb, t, 10);
        return;
    }
    const int wave = tid >> 6, lane = tid & 63;
    const int z = id & 7, h = (id >> 3) & 1, x = (id >> 4) & 3, y = (id >> 6) & 3;

    floatx4_t acc[4][4];
#pragma unroll
    for (int i = 0; i < 4; ++i)
#pragma unroll
        for (int j = 0; j < 4; ++j) acc[i][j] = 0.0f;

    const bf16* Ap = VT + (long long)z * (DOUT * SKV) + (long long)y * 128 * SKV + h * 1024;
    const bf16* Bp = Woffb + (long long)x * 128 * SKV + h * 1024;
    gemm_mainloop(acc, Ap, Bp, SKV, SKV, 1024, (bf16*)smem, (bf16*)(smem + 16384), wave, lane);

    const int wm = (wave & 1) * 64, wn = (wave >> 1) * 64;
    const int lm = lane & 15, quad = lane >> 4;
    float* C = (h ? G32b : G32a) + (long long)z * (DOUT * DIN);
#pragma unroll
    for (int i = 0; i < 4; ++i)
#pragma unroll
        for (int j = 0; j < 4; ++j) {
            const int row0 = y * 128 + wm + i * 16 + quad * 4;
            const int col = x * 128 + wn + j * 16 + lm;
#pragma unroll
            for (int r = 0; r < 4; ++r)
                C[(long long)(row0 + r) * DIN + col] = acc[i][j][r];
        }
}

// ---------------- S-GEMM fp8 + exp epilogue + row sums; ids>=2048 convert G32->Gb ----------------
// grid 2112: s-blocks: z=id%8, x=(id/8)%16, y=(id/8)/16
__global__ __launch_bounds__(256) void s_gemm_exp(
    const u8* __restrict__ Qb8, const u8* __restrict__ Kb8,
    u8* __restrict__ expS8, float* __restrict__ l,
    const float* __restrict__ G32a, const float* __restrict__ G32b,
    bf16* __restrict__ Gb)
{
    __shared__ __align__(16) u8 smem[32768];
    const int tid = threadIdx.x;
    const int id = blockIdx.x;
    if (id >= 2048) {
        // convert G32a+G32b -> Gb (swizzled, rows = 512 bf16 = 1024 B)
        const int base = (id - 2048) * 256 + tid;
        const float4* A4 = (const float4*)G32a;
        const float4* B4 = (const float4*)G32b;
        u8* O = (u8*)Gb;
#pragma unroll 4
        for (int t = 0; t < 32; ++t) {
            const int idx = base + t * 16384;
            float4 a = A4[idx], b = B4[idx];
            bf16x4_t o = { (bf16)(a.x + b.x), (bf16)(a.y + b.y),
                           (bf16)(a.z + b.z), (bf16)(a.w + b.w) };
            const long long boff = (long long)idx * 8;
            const int row = (int)(boff >> 10);
            const int cb = (int)(boff & 1023);
            *(bf16x4_t*)&O[((long long)row << 10) + swz_off(row, cb)] = o;
        }
        return;
    }
    const int wave = tid >> 6, lane = tid & 63;
    const int z = id & 7, x = (id >> 3) & 15, y = (id >> 3) >> 4;

    floatx4_t acc[4][4];
#pragma unroll
    for (int i = 0; i < 4; ++i)
#pragma unroll
        for (int j = 0; j < 4; ++j) acc[i][j] = 0.0f;

    const u8* Ap = Qb8 + ((long long)z * SQ + (long long)y * 128) * DOUT;
    const u8* Bp = Kb8 + ((long long)z * SKV + (long long)x * 128) * DOUT;
    gemm_mainloop_fp8(acc, Ap, Bp, DOUT, DOUT, DOUT, smem, smem + 16384, wave, lane);

    const int wm = (wave & 1) * 64, wn = (wave >> 1) * 64;
    const int lm = lane & 15, quad = lane >> 4;
    u8* C = expS8 + (long long)z * SQ * SKV;
    const long long grow0 = (long long)z * SQ + (long long)y * 128;
#pragma unroll
    for (int i = 0; i < 4; ++i) {
        float rs[4] = {0.f, 0.f, 0.f, 0.f};
#pragma unroll
        for (int j = 0; j < 4; ++j) {
            const int row0 = y * 128 + wm + i * 16 + quad * 4;
            const int col = x * 128 + wn + j * 16 + lm;
#pragma unroll
            for (int r = 0; r < 4; ++r) {
                float e = __expf(acc[i][j][r] * SCORE_SCALE);
                rs[r] += e;
                C[(long long)(row0 + r) * SKV + swz_off(row0 + r, col)] = to_fp8(e * P_STORE_SCALE);
            }
        }
#pragma unroll
        for (int r = 0; r < 4; ++r) {
            float v = rs[r];
            v += __shfl_xor(v, 1, 64);
            v += __shfl_xor(v, 2, 64);
            v += __shfl_xor(v, 4, 64);
            v += __shfl_xor(v, 8, 64);
            if (lm == 0)
                atomicAdd(&l[grow0 + wm + i * 16 + quad * 4 + r], v);
        }
    }
}

// ---------------- out = (expS8 @ V8)*16/l + offset @ G ----------------
// grid 512: z=id%8, x=(id/8)%4, y=(id/8)/4
__global__ __launch_bounds__(256) void out_gemm(
    const u8* __restrict__ expS8, const u8* __restrict__ VT8,
    const bf16* __restrict__ offb, const bf16* __restrict__ Gb,
    const float* __restrict__ l, float* __restrict__ out)
{
    __shared__ __align__(16) u8 smem[32768];
    const int tid = threadIdx.x;
    const int wave = tid >> 6, lane = tid & 63;
    const int id = blockIdx.x;
    const int z = id & 7, x = (id >> 3) & 3, y = (id >> 3) >> 2;

    floatx4_t acc[4][4];
#pragma unroll
    for (int i = 0; i < 4; ++i)
#pragma unroll
        for (int j = 0; j < 4; ++j) acc[i][j] = 0.0f;

    // pass 1 (fp8): expS8 @ VT8^T, K = SKV
    {
        const u8* Ap = expS8 + (long long)z * SQ * SKV + (long long)y * 128 * SKV;
        const u8* Bp = VT8 + (long long)z * DOUT * SKV + (long long)x * 128 * SKV;
        gemm_mainloop_fp8(acc, Ap, Bp, SKV, SKV, SKV, smem, smem + 16384, wave, lane);
    }

    const int wm = (wave & 1) * 64, wn = (wave >> 1) * 64;
    const int lm = lane & 15, quad = lane >> 4;
    const long long grow0 = (long long)z * SQ + (long long)y * 128;

    // scale by 16/l (undo P_STORE_SCALE, normalize softmax)
#pragma unroll
    for (int i = 0; i < 4; ++i)
#pragma unroll
        for (int r = 0; r < 4; ++r) {
            const float inv = P_UNDO_SCALE / l[grow0 + wm + i * 16 + quad * 4 + r];
#pragma unroll
            for (int j = 0; j < 4; ++j) acc[i][j][r] *= inv;
        }

    // pass 2 (bf16): offset @ G, K = DIN
    {
        const bf16* Ap = offb + grow0 * DIN;
        const bf16* Bp = Gb + (long long)z * DOUT * DIN + (long long)x * 128 * DIN;
        gemm_mainloop(acc, Ap, Bp, DIN, DIN, DIN, (bf16*)smem, (bf16*)(smem + 16384), wave, lane);
    }

#pragma unroll
    for (int i = 0; i < 4; ++i)
#pragma unroll
        for (int j = 0; j < 4; ++j) {
            const long long row0 = grow0 + wm + i * 16 + quad * 4;
            const int col = x * 128 + wn + j * 16 + lm;
#pragma unroll
            for (int r = 0; r < 4; ++r)
                out[(row0 + r) * DOUT + col] = acc[i][j][r];
        }
}

extern "C" void kernel_launch(void* const* d_in, const int* in_sizes, int n_in,
                              void* d_out, int out_size, void* d_ws, size_t ws_size,
                              hipStream_t stream) {
    const float* query = (const float*)d_in[0];
    const float* key_ = (const float*)d_in[1];
    const float* value = (const float*)d_in[2];
    const float* offset = (const float*)d_in[3];
    const float* Wq = (const float*)d_in[4];
    const float* Wk = (const float*)d_in[5];
    const float* Wv = (const float*)d_in[6];
    const float* Woff = (const float*)d_in[7];
    float* out = (float*)d_out;

    char* ws = (char*)d_ws;
    const long long NE = (long long)NB * SQ * DIN;  // 8,388,608
    const long long MB = 1048576;

    u8* query8   = (u8*)(ws + 0 * MB);     // 8 MB, fp8 swz
    u8* key8     = (u8*)(ws + 8 * MB);     // 8 MB
    bf16* valueb = (bf16*)(ws + 16 * MB);  // 16 MB, bf16 swz
    bf16* offsetb= (bf16*)(ws + 32 * MB);  // 16 MB, bf16 swz
    u8* Qb8      = (u8*)(ws + 48 * MB);    // 8 MB
    u8* Kb8      = (u8*)(ws + 56 * MB);    // 8 MB
    bf16* VT     = (bf16*)(ws + 64 * MB);  // 16 MB, bf16 swz
    u8* VT8      = (u8*)(ws + 80 * MB);    // 8 MB
    float* G32a  = (float*)(ws + 88 * MB); // 8 MB
    float* G32b  = (float*)(ws + 96 * MB); // 8 MB
    bf16* Gb     = (bf16*)(ws + 104 * MB); // 4 MB, bf16 swz
    u8* WqT8     = (u8*)(ws + 108 * MB);            // 256 KB
    u8* WkT8     = (u8*)(ws + 108 * MB + 262144);   // 256 KB
    bf16* WvT    = (bf16*)(ws + 108 * MB + 524288); // 512 KB, bf16 swz
    bf16* Woffb  = (bf16*)(ws + 109 * MB);          // 2 MB, bf16 swz
    float* lbuf  = (float*)(ws + 111 * MB);         // 64 KB
    u8* expS8    = (u8*)(ws + 112 * MB);   // 32 MB
    // total 144 MB

    // 1. critical-path casts only: query/key fp8+swz, value bf16+swz
    CastArgs ca;
    ca.src[0] = query; ca.dst[0] = query8; ca.n[0] = (int)(NE / 16); ca.mode[0] = 1; ca.rowshift[0] = 9;
    ca.src[1] = key_;  ca.dst[1] = key8;   ca.n[1] = (int)(NE / 16); ca.mode[1] = 1; ca.rowshift[1] = 9;
    ca.src[2] = value; ca.dst[2] = valueb; ca.n[2] = (int)(NE / 8);  ca.mode[2] = 0; ca.rowshift[2] = 10;
    cast_many<<<dim3(4096, 1, 3), 256, 0, stream>>>(ca);

    // 2. weight transposes: Wq,Wk -> fp8 swz x4; Wv -> bf16 swz
    TWArgs tw;
    tw.src[0] = Wq; tw.src[1] = Wk; tw.src[2] = Wv;
    tw.dst[0] = WqT8; tw.dst[1] = WkT8; tw.dst[2] = WvT;
    transpose_w<<<dim3(16, 16, 3), dim3(32, 8), 0, stream>>>(tw);

    // 3. Q,K projections (fp8) + VT projection (bf16) + fused Woff->bf16 cast
    proj_gemm<<<dim3(2048), 256, 0, stream>>>(query8, key8, WqT8, WkT8, Qb8, Kb8,
                                              valueb, WvT, VT, VT8, Woff, Woffb);

    // 4. G = (Woff @ V)^T split-K2 + fused offset->bf16 cast + lbuf zero
    g_gemm<<<dim3(4356), 256, 0, stream>>>(VT, Woffb, G32a, G32b, offset, offsetb, lbuf);

    // 5. expS8 = exp(scores)/16 (fp8) + row sums l; tail blocks convert G32 -> Gb
    s_gemm_exp<<<dim3(2112), 256, 0, stream>>>(Qb8, Kb8, expS8, lbuf, G32a, G32b, Gb);

    // 6. out = (expS8 @ V8)*16/l + offset @ G
    out_gemm<<<dim3(512), 256, 0, stream>>>(expS8, VT8, offsetb, Gb, lbuf, out);
}

// Round 7
// 301.385 us; speedup vs baseline: 1.0166x; 1.0166x over previous
//
#include <hip/hip_runtime.h>
#include <hip/hip_bf16.h>
#include <stdint.h>

typedef __bf16 bf16;
typedef unsigned char u8;
typedef bf16 bf16x4_t __attribute__((ext_vector_type(4)));
typedef bf16 bf16x8_t __attribute__((ext_vector_type(8)));
typedef float floatx4_t __attribute__((ext_vector_type(4)));

#define NB 8
#define SQ 2048
#define SKV 2048
#define DIN 512
#define DOUT 512

// scores = (q*4)(k*4)/16/sqrt(512): 1/(16*sqrt(512))
#define SCORE_SCALE 0.0027621358640099513f
// expS stored as e/16 to stay under fp8 e4m3 max (448)
#define P_STORE_SCALE 0.0625f
#define P_UNDO_SCALE 16.0f

__device__ __forceinline__ void load_lds16(const void* g, void* l) {
    __builtin_amdgcn_global_load_lds(
        (const __attribute__((address_space(1))) unsigned int*)g,
        (__attribute__((address_space(3))) unsigned int*)l, 16, 0, 0);
}

// Counted-vmcnt waits + raw barrier (T4): keep the newest prefetch in flight
// across the barrier instead of __syncthreads()'s vmcnt(0) drain. sched_barrier
// fences per rule #18 (compiler may otherwise hoist LDS reads past asm waits).
__device__ __forceinline__ void wait_vm4() {
    asm volatile("s_waitcnt vmcnt(4)" ::: "memory");
    __builtin_amdgcn_sched_barrier(0);
}
__device__ __forceinline__ void wait_vm0() {
    asm volatile("s_waitcnt vmcnt(0)" ::: "memory");
    __builtin_amdgcn_sched_barrier(0);
}
__device__ __forceinline__ void hard_barrier() {
    __builtin_amdgcn_sched_barrier(0);
    __builtin_amdgcn_s_barrier();
    __builtin_amdgcn_sched_barrier(0);
}

__device__ __forceinline__ u8 to_fp8(float f) {
    int v = __builtin_amdgcn_cvt_pk_fp8_f32(f, 0.f, 0, false);
    return (u8)(v & 0xff);
}
__device__ __forceinline__ unsigned int pack_fp8x4(float a, float b, float c, float d) {
    int lo = __builtin_amdgcn_cvt_pk_fp8_f32(a, b, 0, false);
    int all = __builtin_amdgcn_cvt_pk_fp8_f32(c, d, lo, true);
    return (unsigned int)all;
}

// 16-B-granule XOR swizzle within each 64-B k-block, key = (row>>1)&3.
// Spreads same-granule rows across all 8 bank groups -> ~2-way (free).
// Producers write with it; LDS readers undo it.
__device__ __forceinline__ int swz_off(int row, int col) {
    return (col & ~63) | ((((col >> 4) & 3) ^ ((row >> 1) & 3)) << 4) | (col & 15);
}

// bf16 cast helper: 8 consecutive f32 -> one 16-B swizzled store.
__device__ __forceinline__ void cast_bf16_16B(const float4* s4, u8* d, int t, int rs) {
    const long long b0 = (long long)t * 16;
    const int row = (int)(b0 >> rs);
    const int cb = (int)(b0 & ((1 << rs) - 1));
    float4 f0 = s4[t * 2], f1 = s4[t * 2 + 1];
    bf16x8_t o = { (bf16)f0.x, (bf16)f0.y, (bf16)f0.z, (bf16)f0.w,
                   (bf16)f1.x, (bf16)f1.y, (bf16)f1.z, (bf16)f1.w };
    *(bf16x8_t*)&d[((long long)row << rs) + swz_off(row, cb)] = o;
}

// ---------------- cast: query/key -> fp8(swz), value -> bf16(swz) ----------------
struct CastArgs {
    const float* src[3];
    void* dst[3];
    int n[3];
    int mode[3];     // 0=bf16 swz, 1=fp8 swz
    int rowshift[3];
};
__global__ __launch_bounds__(256) void cast_many(CastArgs a) {
    const int z = blockIdx.z;
    const int t = blockIdx.x * 256 + threadIdx.x;
    if (t >= a.n[z]) return;
    const float4* s4 = (const float4*)a.src[z];
    u8* d = (u8*)a.dst[z];
    const int rs = a.rowshift[z];
    if (a.mode[z] == 1) {
        const long long b0 = (long long)t * 16;
        const int row = (int)(b0 >> rs);
        const int cb = (int)(b0 & ((1 << rs) - 1));
        u8* dst = &d[((long long)row << rs) + swz_off(row, cb)];
        float4 f[4];
#pragma unroll
        for (int k = 0; k < 4; ++k) f[k] = s4[t * 4 + k];
        uint4 o;
        o.x = pack_fp8x4(f[0].x, f[0].y, f[0].z, f[0].w);
        o.y = pack_fp8x4(f[1].x, f[1].y, f[1].z, f[1].w);
        o.z = pack_fp8x4(f[2].x, f[2].y, f[2].z, f[2].w);
        o.w = pack_fp8x4(f[3].x, f[3].y, f[3].z, f[3].w);
        *(uint4*)dst = o;
    } else {
        cast_bf16_16B(s4, d, t, rs);
    }
}

// ---------------- weight transpose f32[512,512] -> fp8(swz, x4) for Wq/Wk, bf16(swz) for Wv ----------------
struct TWArgs { const float* src[3]; void* dst[3]; };
__global__ void transpose_w(TWArgs a) {
    __shared__ float t[32][33];
    const float* src = a.src[blockIdx.z];
    int tx = threadIdx.x, ty = threadIdx.y;
    int x0 = blockIdx.x * 32, y0 = blockIdx.y * 32;
#pragma unroll
    for (int j = 0; j < 4; ++j)
        t[ty + 8 * j][tx] = src[(y0 + ty + 8 * j) * DIN + x0 + tx];
    __syncthreads();
    if (blockIdx.z <= 1) {
        u8* d8 = (u8*)a.dst[blockIdx.z];
#pragma unroll
        for (int j = 0; j < 4; ++j) {
            int row = x0 + ty + 8 * j, col = y0 + tx;
            d8[row * 512 + swz_off(row, col)] = to_fp8(t[tx][ty + 8 * j] * 4.0f);
        }
    } else {
        u8* db = (u8*)a.dst[2];
#pragma unroll
        for (int j = 0; j < 4; ++j) {
            int row = x0 + ty + 8 * j, cb = (y0 + tx) * 2;
            *(bf16*)&db[(long long)row * 1024 + swz_off(row, cb)] = (bf16)t[tx][ty + 8 * j];
        }
    }
}

// ---------------- bf16 NT mainloop, BK=32, TRIPLE-buffered, prefetch depth 2 ----------------
// Per step: issue STAGE(s+2) -> compute buf[s] -> wait vmcnt(4) (buf[s+1] done,
// buf[s+2] stays in flight) -> s_barrier. The drain-to-0 of __syncthreads was
// the 2-phase structure's ~26% MfmaUtil ceiling.
// LDS per operand: 3 bufs x 8192 B.
__device__ __forceinline__ void gemm_mainloop(
    floatx4_t (&acc)[4][4], const bf16* __restrict__ Ap, const bf16* __restrict__ Bp,
    int lda, int ldb, int K, bf16* As, bf16* Bs, int wave, int lane)
{
    const int wm = (wave & 1) * 64, wn = (wave >> 1) * 64;
    const int lm = lane & 15, quad = lane >> 4;
    const int srow = lane >> 2, scol = (lane & 3) * 8;
    const int key = (lm >> 1) & 3;

    auto STAGE = [&](int buf, int k0) {
#pragma unroll
        for (int t = 0; t < 2; ++t) {
            const int r0 = (wave * 2 + t) * 16;
            load_lds16(Ap + (long long)(r0 + srow) * lda + (k0 + scol),
                       &As[buf * 4096 + r0 * 32]);
            load_lds16(Bp + (long long)(r0 + srow) * ldb + (k0 + scol),
                       &Bs[buf * 4096 + r0 * 32]);
        }
    };

    const int nsteps = K >> 5;
    STAGE(0, 0);
    STAGE(1, 32);
    wait_vm4();
    hard_barrier();
    int cur = 0, stg = 2;
    for (int s = 0; s < nsteps; ++s) {
        if (s + 2 < nsteps) STAGE(stg, (s + 2) << 5);
        bf16x8_t af[4], bfr[4];
#pragma unroll
        for (int i = 0; i < 4; ++i)
            af[i] = *(const bf16x8_t*)&As[cur * 4096 + (wm + i * 16 + lm) * 32 + (quad ^ key) * 8];
#pragma unroll
        for (int i = 0; i < 4; ++i)
            bfr[i] = *(const bf16x8_t*)&Bs[cur * 4096 + (wn + i * 16 + lm) * 32 + (quad ^ key) * 8];
#pragma unroll
        for (int i = 0; i < 4; ++i)
#pragma unroll
            for (int j = 0; j < 4; ++j)
                acc[i][j] = __builtin_amdgcn_mfma_f32_16x16x32_bf16(af[i], bfr[j], acc[i][j], 0, 0, 0);
        if (s + 1 < nsteps) {
            if (s + 2 < nsteps) wait_vm4(); else wait_vm0();
        }
        hard_barrier();
        cur = (cur == 2) ? 0 : cur + 1;
        stg = (stg == 2) ? 0 : stg + 1;
    }
}

// ---------------- fp8 NT mainloop, BK=64, TRIPLE-buffered, prefetch depth 2 ----------------
// LDS per operand: 3 bufs x 8192 B.
__device__ __forceinline__ void gemm_mainloop_fp8(
    floatx4_t (&acc)[4][4], const u8* __restrict__ Ap, const u8* __restrict__ Bp,
    int lda, int ldb, int K, u8* As, u8* Bs, int wave, int lane)
{
    const int wm = (wave & 1) * 64, wn = (wave >> 1) * 64;
    const int lm = lane & 15, quad = lane >> 4;
    const int srow = lane >> 2, scol = (lane & 3) * 16;  // 16 rows x 64 B per inst
    const int key = (lm >> 1) & 3;
    const int inner = (quad & 1) * 8;
    const int gh = quad >> 1;

    auto STAGE = [&](int buf, int k0) {
#pragma unroll
        for (int t = 0; t < 2; ++t) {
            const int r0 = (wave * 2 + t) * 16;
            load_lds16(Ap + (long long)(r0 + srow) * lda + k0 + scol, &As[buf * 8192 + r0 * 64]);
            load_lds16(Bp + (long long)(r0 + srow) * ldb + k0 + scol, &Bs[buf * 8192 + r0 * 64]);
        }
    };

    const int nsteps = K >> 6;
    STAGE(0, 0);
    STAGE(1, 64);
    wait_vm4();
    hard_barrier();
    int cur = 0, stg = 2;
    for (int s = 0; s < nsteps; ++s) {
        if (s + 2 < nsteps) STAGE(stg, (s + 2) << 6);
#pragma unroll
        for (int p = 0; p < 2; ++p) {
            const int gL = p * 2 + gh;
            const int koff = ((gL ^ key) << 4) + inner;  // undo producer swizzle
            long long a[4], b[4];
#pragma unroll
            for (int i = 0; i < 4; ++i)
                a[i] = *(const long long*)&As[cur * 8192 + (wm + i * 16 + lm) * 64 + koff];
#pragma unroll
            for (int i = 0; i < 4; ++i)
                b[i] = *(const long long*)&Bs[cur * 8192 + (wn + i * 16 + lm) * 64 + koff];
#pragma unroll
            for (int i = 0; i < 4; ++i)
#pragma unroll
                for (int j = 0; j < 4; ++j)
                    acc[i][j] = __builtin_amdgcn_mfma_f32_16x16x32_fp8_fp8(a[i], b[j], acc[i][j], 0, 0, 0);
        }
        if (s + 1 < nsteps) {
            if (s + 2 < nsteps) wait_vm4(); else wait_vm0();
        }
        hard_barrier();
        cur = (cur == 2) ? 0 : cur + 1;
        stg = (stg == 2) ? 0 : stg + 1;
    }
}

// ---------------- phase 1: Q/K projections (fp8) + VT projection (bf16) + Woff cast ----------------
__global__ __launch_bounds__(256) void proj_gemm(
    const u8* __restrict__ query8, const u8* __restrict__ key8,
    const u8* __restrict__ WqT8, const u8* __restrict__ WkT8,
    u8* __restrict__ Qb8, u8* __restrict__ Kb8,
    const bf16* __restrict__ valueb, const bf16* __restrict__ WvT,
    bf16* __restrict__ VT, u8* __restrict__ VT8,
    const float* __restrict__ Woff, bf16* __restrict__ Woffb)
{
    __shared__ __align__(16) u8 smem[49152];
    const int tid = threadIdx.x;
    const int id = blockIdx.x;
    if (id >= 1536) {
        const int t = (id - 1536) * 256 + tid;
        cast_bf16_16B((const float4*)Woff, (u8*)Woffb, t, 12);
        return;
    }
    const int wave = tid >> 6, lane = tid & 63;
    const int wm = (wave & 1) * 64, wn = (wave >> 1) * 64;
    const int lm = lane & 15, quad = lane >> 4;

    floatx4_t acc[4][4];
#pragma unroll
    for (int i = 0; i < 4; ++i)
#pragma unroll
        for (int j = 0; j < 4; ++j) acc[i][j] = 0.0f;

    if (id < 1024) {
        const int xcd = id & 7, t = id >> 3, m = t & 3;
        const int gg = xcd + 8 * (t >> 2);
        const int y = gg & 127, z = gg >> 7;
        const u8* Ap = (z ? key8 : query8) + (long long)y * 128 * DIN;
        const u8* Bp = (z ? WkT8 : WqT8) + (long long)m * 128 * DIN;
        gemm_mainloop_fp8(acc, Ap, Bp, DIN, DIN, DIN, smem, smem + 24576, wave, lane);
        u8* C = z ? Kb8 : Qb8;
#pragma unroll
        for (int i = 0; i < 4; ++i)
#pragma unroll
            for (int j = 0; j < 4; ++j) {
                const int row0 = y * 128 + wm + i * 16 + quad * 4;
                const int col = m * 128 + wn + j * 16 + lm;
#pragma unroll
                for (int r = 0; r < 4; ++r)
                    C[(long long)(row0 + r) * DOUT + swz_off(row0 + r, col)] = to_fp8(acc[i][j][r]);
            }
    } else {
        const int id2 = id - 1024;
        const int z = id2 & 7, r2 = id2 >> 3;
        const int ym = r2 & 3, xn = r2 >> 2;
        const bf16* Ap = WvT + (long long)ym * 128 * DIN;
        const bf16* Bp = valueb + (long long)z * (SKV * DIN) + (long long)xn * 128 * DIN;
        gemm_mainloop(acc, Ap, Bp, DIN, DIN, DIN, (bf16*)smem, (bf16*)(smem + 24576), wave, lane);
        u8* C = (u8*)(VT + (long long)z * (DOUT * SKV));
        u8* C8 = VT8 + (long long)z * (DOUT * SKV);
#pragma unroll
        for (int i = 0; i < 4; ++i)
#pragma unroll
            for (int j = 0; j < 4; ++j) {
                const int row0 = ym * 128 + wm + i * 16 + quad * 4;
                const int col = xn * 128 + wn + j * 16 + lm;
#pragma unroll
                for (int r = 0; r < 4; ++r) {
                    float v = acc[i][j][r];
                    const int rr = row0 + r;
                    *(bf16*)&C[(long long)rr * (SKV * 2) + swz_off(rr, col * 2)] = (bf16)v;
                    C8[(long long)rr * SKV + swz_off(rr, col)] = to_fp8(v);
                }
            }
    }
}

// ---------------- G split-K2 + fused offset cast + lbuf zero ----------------
__global__ __launch_bounds__(256) void g_gemm(
    const bf16* __restrict__ VT, const bf16* __restrict__ Woffb,
    float* __restrict__ G32a, float* __restrict__ G32b,
    const float* __restrict__ offset, bf16* __restrict__ offsetb,
    float* __restrict__ lbuf)
{
    __shared__ __align__(16) u8 smem[49152];
    const int tid = threadIdx.x;
    const int id = blockIdx.x;
    if (id >= 4352) {
        float4* d4 = (float4*)lbuf;
        const int t = (id - 4352) * 256 + tid;
#pragma unroll
        for (int k = 0; k < 4; ++k)
            d4[t * 4 + k] = make_float4(0.f, 0.f, 0.f, 0.f);
        return;
    }
    if (id >= 256) {
        const int t = (id - 256) * 256 + tid;
        cast_bf16_16B((const float4*)offset, (u8*)offsetb, t, 10);
        return;
    }
    const int wave = tid >> 6, lane = tid & 63;
    const int z = id & 7, h = (id >> 3) & 1, x = (id >> 4) & 3, y = (id >> 6) & 3;

    floatx4_t acc[4][4];
#pragma unroll
    for (int i = 0; i < 4; ++i)
#pragma unroll
        for (int j = 0; j < 4; ++j) acc[i][j] = 0.0f;

    const bf16* Ap = VT + (long long)z * (DOUT * SKV) + (long long)y * 128 * SKV + h * 1024;
    const bf16* Bp = Woffb + (long long)x * 128 * SKV + h * 1024;
    gemm_mainloop(acc, Ap, Bp, SKV, SKV, 1024, (bf16*)smem, (bf16*)(smem + 24576), wave, lane);

    const int wm = (wave & 1) * 64, wn = (wave >> 1) * 64;
    const int lm = lane & 15, quad = lane >> 4;
    float* C = (h ? G32b : G32a) + (long long)z * (DOUT * DIN);
#pragma unroll
    for (int i = 0; i < 4; ++i)
#pragma unroll
        for (int j = 0; j < 4; ++j) {
            const int row0 = y * 128 + wm + i * 16 + quad * 4;
            const int col = x * 128 + wn + j * 16 + lm;
#pragma unroll
            for (int r = 0; r < 4; ++r)
                C[(long long)(row0 + r) * DIN + col] = acc[i][j][r];
        }
}

// ---------------- S-GEMM fp8 + exp epilogue + row sums; ids>=2048 convert G32->Gb ----------------
__global__ __launch_bounds__(256) void s_gemm_exp(
    const u8* __restrict__ Qb8, const u8* __restrict__ Kb8,
    u8* __restrict__ expS8, float* __restrict__ l,
    const float* __restrict__ G32a, const float* __restrict__ G32b,
    bf16* __restrict__ Gb)
{
    __shared__ __align__(16) u8 smem[49152];
    const int tid = threadIdx.x;
    const int id = blockIdx.x;
    if (id >= 2048) {
        const int base = (id - 2048) * 256 + tid;
        const float4* A4 = (const float4*)G32a;
        const float4* B4 = (const float4*)G32b;
        u8* O = (u8*)Gb;
#pragma unroll 4
        for (int t = 0; t < 32; ++t) {
            const int idx = base + t * 16384;
            float4 a = A4[idx], b = B4[idx];
            bf16x4_t o = { (bf16)(a.x + b.x), (bf16)(a.y + b.y),
                           (bf16)(a.z + b.z), (bf16)(a.w + b.w) };
            const long long boff = (long long)idx * 8;
            const int row = (int)(boff >> 10);
            const int cb = (int)(boff & 1023);
            *(bf16x4_t*)&O[((long long)row << 10) + swz_off(row, cb)] = o;
        }
        return;
    }
    const int wave = tid >> 6, lane = tid & 63;
    const int z = id & 7, x = (id >> 3) & 15, y = (id >> 3) >> 4;

    floatx4_t acc[4][4];
#pragma unroll
    for (int i = 0; i < 4; ++i)
#pragma unroll
        for (int j = 0; j < 4; ++j) acc[i][j] = 0.0f;

    const u8* Ap = Qb8 + ((long long)z * SQ + (long long)y * 128) * DOUT;
    const u8* Bp = Kb8 + ((long long)z * SKV + (long long)x * 128) * DOUT;
    gemm_mainloop_fp8(acc, Ap, Bp, DOUT, DOUT, DOUT, smem, smem + 24576, wave, lane);

    const int wm = (wave & 1) * 64, wn = (wave >> 1) * 64;
    const int lm = lane & 15, quad = lane >> 4;
    u8* C = expS8 + (long long)z * SQ * SKV;
    const long long grow0 = (long long)z * SQ + (long long)y * 128;
#pragma unroll
    for (int i = 0; i < 4; ++i) {
        float rs[4] = {0.f, 0.f, 0.f, 0.f};
#pragma unroll
        for (int j = 0; j < 4; ++j) {
            const int row0 = y * 128 + wm + i * 16 + quad * 4;
            const int col = x * 128 + wn + j * 16 + lm;
#pragma unroll
            for (int r = 0; r < 4; ++r) {
                float e = __expf(acc[i][j][r] * SCORE_SCALE);
                rs[r] += e;
                C[(long long)(row0 + r) * SKV + swz_off(row0 + r, col)] = to_fp8(e * P_STORE_SCALE);
            }
        }
#pragma unroll
        for (int r = 0; r < 4; ++r) {
            float v = rs[r];
            v += __shfl_xor(v, 1, 64);
            v += __shfl_xor(v, 2, 64);
            v += __shfl_xor(v, 4, 64);
            v += __shfl_xor(v, 8, 64);
            if (lm == 0)
                atomicAdd(&l[grow0 + wm + i * 16 + quad * 4 + r], v);
        }
    }
}

// ---------------- out = (expS8 @ V8)*16/l + offset @ G ----------------
__global__ __launch_bounds__(256) void out_gemm(
    const u8* __restrict__ expS8, const u8* __restrict__ VT8,
    const bf16* __restrict__ offb, const bf16* __restrict__ Gb,
    const float* __restrict__ l, float* __restrict__ out)
{
    __shared__ __align__(16) u8 smem[49152];
    const int tid = threadIdx.x;
    const int wave = tid >> 6, lane = tid & 63;
    const int id = blockIdx.x;
    const int z = id & 7, x = (id >> 3) & 3, y = (id >> 3) >> 2;

    floatx4_t acc[4][4];
#pragma unroll
    for (int i = 0; i < 4; ++i)
#pragma unroll
        for (int j = 0; j < 4; ++j) acc[i][j] = 0.0f;

    // pass 1 (fp8): expS8 @ VT8^T, K = SKV
    {
        const u8* Ap = expS8 + (long long)z * SQ * SKV + (long long)y * 128 * SKV;
        const u8* Bp = VT8 + (long long)z * DOUT * SKV + (long long)x * 128 * SKV;
        gemm_mainloop_fp8(acc, Ap, Bp, SKV, SKV, SKV, smem, smem + 24576, wave, lane);
    }

    const int wm = (wave & 1) * 64, wn = (wave >> 1) * 64;
    const int lm = lane & 15, quad = lane >> 4;
    const long long grow0 = (long long)z * SQ + (long long)y * 128;

    // scale by 16/l (undo P_STORE_SCALE, normalize softmax)
#pragma unroll
    for (int i = 0; i < 4; ++i)
#pragma unroll
        for (int r = 0; r < 4; ++r) {
            const float inv = P_UNDO_SCALE / l[grow0 + wm + i * 16 + quad * 4 + r];
#pragma unroll
            for (int j = 0; j < 4; ++j) acc[i][j][r] *= inv;
        }

    // pass 2 (bf16): offset @ G, K = DIN
    {
        const bf16* Ap = offb + grow0 * DIN;
        const bf16* Bp = Gb + (long long)z * DOUT * DIN + (long long)x * 128 * DIN;
        gemm_mainloop(acc, Ap, Bp, DIN, DIN, DIN, (bf16*)smem, (bf16*)(smem + 24576), wave, lane);
    }

#pragma unroll
    for (int i = 0; i < 4; ++i)
#pragma unroll
        for (int j = 0; j < 4; ++j) {
            const long long row0 = grow0 + wm + i * 16 + quad * 4;
            const int col = x * 128 + wn + j * 16 + lm;
#pragma unroll
            for (int r = 0; r < 4; ++r)
                out[(row0 + r) * DOUT + col] = acc[i][j][r];
        }
}

extern "C" void kernel_launch(void* const* d_in, const int* in_sizes, int n_in,
                              void* d_out, int out_size, void* d_ws, size_t ws_size,
                              hipStream_t stream) {
    const float* query = (const float*)d_in[0];
    const float* key_ = (const float*)d_in[1];
    const float* value = (const float*)d_in[2];
    const float* offset = (const float*)d_in[3];
    const float* Wq = (const float*)d_in[4];
    const float* Wk = (const float*)d_in[5];
    const float* Wv = (const float*)d_in[6];
    const float* Woff = (const float*)d_in[7];
    float* out = (float*)d_out;

    char* ws = (char*)d_ws;
    const long long NE = (long long)NB * SQ * DIN;  // 8,388,608
    const long long MB = 1048576;

    u8* query8   = (u8*)(ws + 0 * MB);     // 8 MB, fp8 swz
    u8* key8     = (u8*)(ws + 8 * MB);     // 8 MB
    bf16* valueb = (bf16*)(ws + 16 * MB);  // 16 MB, bf16 swz
    bf16* offsetb= (bf16*)(ws + 32 * MB);  // 16 MB, bf16 swz
    u8* Qb8      = (u8*)(ws + 48 * MB);    // 8 MB
    u8* Kb8      = (u8*)(ws + 56 * MB);    // 8 MB
    bf16* VT     = (bf16*)(ws + 64 * MB);  // 16 MB, bf16 swz
    u8* VT8      = (u8*)(ws + 80 * MB);    // 8 MB
    float* G32a  = (float*)(ws + 88 * MB); // 8 MB
    float* G32b  = (float*)(ws + 96 * MB); // 8 MB
    bf16* Gb     = (bf16*)(ws + 104 * MB); // 4 MB, bf16 swz
    u8* WqT8     = (u8*)(ws + 108 * MB);            // 256 KB
    u8* WkT8     = (u8*)(ws + 108 * MB + 262144);   // 256 KB
    bf16* WvT    = (bf16*)(ws + 108 * MB + 524288); // 512 KB, bf16 swz
    bf16* Woffb  = (bf16*)(ws + 109 * MB);          // 2 MB, bf16 swz
    float* lbuf  = (float*)(ws + 111 * MB);         // 64 KB
    u8* expS8    = (u8*)(ws + 112 * MB);   // 32 MB
    // total 144 MB

    // 1. critical-path casts only: query/key fp8+swz, value bf16+swz
    CastArgs ca;
    ca.src[0] = query; ca.dst[0] = query8; ca.n[0] = (int)(NE / 16); ca.mode[0] = 1; ca.rowshift[0] = 9;
    ca.src[1] = key_;  ca.dst[1] = key8;   ca.n[1] = (int)(NE / 16); ca.mode[1] = 1; ca.rowshift[1] = 9;
    ca.src[2] = value; ca.dst[2] = valueb; ca.n[2] = (int)(NE / 8);  ca.mode[2] = 0; ca.rowshift[2] = 10;
    cast_many<<<dim3(4096, 1, 3), 256, 0, stream>>>(ca);

    // 2. weight transposes: Wq,Wk -> fp8 swz x4; Wv -> bf16 swz
    TWArgs tw;
    tw.src[0] = Wq; tw.src[1] = Wk; tw.src[2] = Wv;
    tw.dst[0] = WqT8; tw.dst[1] = WkT8; tw.dst[2] = WvT;
    transpose_w<<<dim3(16, 16, 3), dim3(32, 8), 0, stream>>>(tw);

    // 3. Q,K projections (fp8) + VT projection (bf16) + fused Woff->bf16 cast
    proj_gemm<<<dim3(2048), 256, 0, stream>>>(query8, key8, WqT8, WkT8, Qb8, Kb8,
                                              valueb, WvT, VT, VT8, Woff, Woffb);

    // 4. G = (Woff @ V)^T split-K2 + fused offset->bf16 cast + lbuf zero
    g_gemm<<<dim3(4356), 256, 0, stream>>>(VT, Woffb, G32a, G32b, offset, offsetb, lbuf);

    // 5. expS8 = exp(scores)/16 (fp8) + row sums l; tail blocks convert G32 -> Gb
    s_gemm_exp<<<dim3(2112), 256, 0, stream>>>(Qb8, Kb8, expS8, lbuf, G32a, G32b, Gb);

    // 6. out = (expS8 @ V8)*16/l + offset @ G
    out_gemm<<<dim3(512), 256, 0, stream>>>(expS8, VT8, offsetb, Gb, lbuf, out);
}